// Round 14
// baseline (146.830 us; speedup 1.0000x reference)
//
#include <hip/hip_runtime.h>
#include <math.h>

#define BATCH 4
#define SEQ   1024
#define EMB   1024
#define HEADS 16
#define HD    64
#define MTOT  (BATCH*SEQ)   // 4096

typedef float    f32x4 __attribute__((ext_vector_type(4)));
typedef float    vf4   __attribute__((ext_vector_type(4)));
typedef _Float16 f16;
typedef _Float16 f16x4 __attribute__((ext_vector_type(4)));
typedef _Float16 f16x8 __attribute__((ext_vector_type(8)));

// ---- conversion: x (4096 rows) + 4 weights (4096 rows) -> fp16 ------------
__global__ __launch_bounds__(256) void convert_all(
    const float* __restrict__ x,
    const float* __restrict__ wq, const float* __restrict__ wk,
    const float* __restrict__ wv, const float* __restrict__ wo,
    f16* __restrict__ xh, f16* __restrict__ wh)
{
    const int bid = blockIdx.x;          // 0..8191
    const float* src;
    f16* dst;
    if (bid < 4096) {
        src = x + ((size_t)bid << 10);
        dst = xh + ((size_t)bid << 10);
    } else {
        int t  = bid - 4096;
        int mi = t >> 10, r = t & 1023;
        const float* in = (mi == 0) ? wq : (mi == 1) ? wk : (mi == 2) ? wv : wo;
        src = in + ((size_t)r << 10);
        dst = wh + ((size_t)mi << 20) + ((size_t)r << 10);
    }
    int o = threadIdx.x << 2;
    float4 v = *(const float4*)(src + o);
    f16x4 h;
    h.x = (f16)v.x; h.y = (f16)v.y; h.z = (f16)v.z; h.w = (f16)v.w;
    *(f16x4*)(dst + o) = h;
}

// ---- fp16 single-pass MFMA GEMM tile: C = A @ W^T -------------------------
#define BM  128
#define BN  128
#define LDT 72   // f16 elems per padded LDS row

__device__ __forceinline__ void mfma_gemm_tile(
    const f16* __restrict__ A, const f16* __restrict__ B,
    int m0, int n0, f32x4 acc[4][4], f16* SMEM)
{
    f16* As = SMEM;
    f16* Bs = SMEM + BM * LDT;
    const int tid  = threadIdx.x;
    const int lane = tid & 63;
    const int w    = tid >> 6;
    const int wr   = w >> 1, wc = w & 1;
    const int fr   = lane & 15;
    const int kb   = lane >> 4;

#pragma unroll
    for (int i = 0; i < 4; ++i)
#pragma unroll
        for (int j = 0; j < 4; ++j) acc[i][j] = (f32x4){0.f, 0.f, 0.f, 0.f};

    f16x8 ra[4], rb[4];
#define LOAD_STEP(KT)                                                          \
    {                                                                          \
        int k0 = (KT) * 64;                                                    \
        _Pragma("unroll")                                                      \
        for (int i = 0; i < 4; ++i) {                                          \
            int c = tid + (i << 8);                                            \
            int row = c >> 3, cc = (c & 7) << 3;                               \
            ra[i] = *(const f16x8*)(A + ((size_t)(m0 + row) << 10) + k0 + cc); \
            rb[i] = *(const f16x8*)(B + ((size_t)(n0 + row) << 10) + k0 + cc); \
        }                                                                      \
    }

    LOAD_STEP(0);
    for (int kt = 0; kt < 16; ++kt) {
        __syncthreads();
#pragma unroll
        for (int i = 0; i < 4; ++i) {
            int c = tid + (i << 8);
            int row = c >> 3, cc = (c & 7) << 3;
            *(f16x8*)&As[row * LDT + cc] = ra[i];
            *(f16x8*)&Bs[row * LDT + cc] = rb[i];
        }
        if (kt + 1 < 16) LOAD_STEP(kt + 1);
        __syncthreads();
#pragma unroll
        for (int kc = 0; kc < 2; ++kc) {
            f16x8 aF[4], bF[4];
#pragma unroll
            for (int i = 0; i < 4; ++i)
                aF[i] = *(const f16x8*)&As[(wr * 64 + i * 16 + fr) * LDT + kc * 32 + kb * 8];
#pragma unroll
            for (int j = 0; j < 4; ++j)
                bF[j] = *(const f16x8*)&Bs[(wc * 64 + j * 16 + fr) * LDT + kc * 32 + kb * 8];
#pragma unroll
            for (int i = 0; i < 4; ++i)
#pragma unroll
                for (int j = 0; j < 4; ++j)
                    acc[i][j] = __builtin_amdgcn_mfma_f32_16x16x32_f16(
                        aF[i], bF[j], acc[i][j], 0, 0, 0);
        }
    }
#undef LOAD_STEP
}

// QKV: Q,K fp16 row-major (b,h,s,d); V in frag layout VF[bh][s/32][d][(s%32)]
__global__ __launch_bounds__(256, 2) void qkv_mfma(
    const f16* __restrict__ xh, const f16* __restrict__ wh,
    const float* __restrict__ bq, const float* __restrict__ bk,
    const float* __restrict__ bv,
    f16* __restrict__ qh, f16* __restrict__ kh, f16* __restrict__ vf)
{
    __shared__ __align__(16) f16 SMEM[2 * BM * LDT];   // 36 KB
    const int z = blockIdx.z;
    const f16* Bm = wh + ((size_t)z << 20);
    const float* bias = (z == 0) ? bq : (z == 1) ? bk : bv;
    const int m0 = blockIdx.y * BM, n0 = blockIdx.x * BN;
    f32x4 acc[4][4];
    mfma_gemm_tile(xh, Bm, m0, n0, acc, SMEM);

    const int tid  = threadIdx.x;
    const int lane = tid & 63;
    const int w    = tid >> 6;
    const int wr   = w >> 1, wc = w & 1;
    const int fr   = lane & 15;
    const int rg   = lane >> 4;
    const int LDC  = 136;
    const int b = m0 >> 10, sbase = m0 & 1023;

    __syncthreads();   // gemm LDS reads done
    if (z < 2) {
        f16* p = (z == 0) ? qh : kh;
#pragma unroll
        for (int i = 0; i < 4; ++i)
#pragma unroll
            for (int j = 0; j < 4; ++j) {
                int nn = wc * 64 + j * 16 + fr;
                float bv_ = bias[n0 + nn];
#pragma unroll
                for (int r = 0; r < 4; ++r) {
                    int mm = wr * 64 + i * 16 + rg * 4 + r;
                    SMEM[mm * LDC + nn] = (f16)(acc[i][j][r] + bv_);
                }
            }
        __syncthreads();
#pragma unroll
        for (int t = 0; t < 8; ++t) {
            int idx = tid + (t << 8);
            int row = idx >> 4, ch = idx & 15;
            int n8 = n0 + ch * 8;
            int h = n8 >> 6, d = n8 & 63;
            f16x8 v = *(const f16x8*)&SMEM[row * LDC + ch * 8];
            *(f16x8*)(p + ((size_t)((b * HEADS + h) * SEQ + sbase + row)) * HD + d) = v;
        }
    } else {
        // transposed bounce SMEM[n][m] -> VF frag layout
#pragma unroll
        for (int i = 0; i < 4; ++i)
#pragma unroll
            for (int j = 0; j < 4; ++j) {
                int nn = wc * 64 + j * 16 + fr;
                float bv_ = bias[n0 + nn];
#pragma unroll
                for (int r = 0; r < 4; ++r) {
                    int mm = wr * 64 + i * 16 + rg * 4 + r;
                    SMEM[nn * LDC + mm] = (f16)(acc[i][j][r] + bv_);
                }
            }
        __syncthreads();
        // VF: addr = bh*65536 + (s>>5)*2048 + d*32 + (s&31)
#pragma unroll
        for (int t = 0; t < 8; ++t) {
            int idx = tid + (t << 8);
            int mch = idx & 15;
            int col = idx >> 4;                  // 0..127
            int n8 = n0 + col;
            int h = n8 >> 6, d = n8 & 63;
            int s0 = sbase + mch * 8;
            f16x8 v = *(const f16x8*)&SMEM[col * LDC + mch * 8];
            size_t a = ((size_t)(b * HEADS + h) << 16) +
                       (size_t)(s0 >> 5) * 2048 + d * 32 + (s0 & 31);
            *(f16x8*)(vf + a) = v;
        }
    }
}

// OPROJ: ctx fp16 @ wo^T + bo -> out fp32, LDS-bounced float4 stores.
__global__ __launch_bounds__(256, 2) void oproj_mfma(
    const f16* __restrict__ ch, const f16* __restrict__ wh,
    const float* __restrict__ bo, float* __restrict__ out)
{
    __shared__ __align__(16) f16 SMEM[2 * BM * LDT];
    const f16* Bm = wh + ((size_t)3 << 20);
    const int m0 = blockIdx.y * BM, n0 = blockIdx.x * BN;
    f32x4 acc[4][4];
    mfma_gemm_tile(ch, Bm, m0, n0, acc, SMEM);

    const int tid  = threadIdx.x;
    const int lane = tid & 63;
    const int w    = tid >> 6;
    const int wr   = w >> 1, wc = w & 1;
    const int fr   = lane & 15;
    const int rg   = lane >> 4;
    float* Cf = (float*)SMEM;            // 64 x 132 fp32 half-tile
    const int LDCf = 132;

#pragma unroll
    for (int half = 0; half < 2; ++half) {
        __syncthreads();
        if (wr == half) {
#pragma unroll
            for (int i = 0; i < 4; ++i)
#pragma unroll
                for (int j = 0; j < 4; ++j) {
                    int nn = wc * 64 + j * 16 + fr;
                    float bv_ = bo[n0 + nn];
#pragma unroll
                    for (int r = 0; r < 4; ++r)
                        Cf[(i * 16 + rg * 4 + r) * LDCf + nn] = acc[i][j][r] + bv_;
                }
        }
        __syncthreads();
#pragma unroll
        for (int t = 0; t < 8; ++t) {
            int idx = tid + (t << 8);
            int row = idx >> 5, c4 = (idx & 31) << 2;
            vf4 v = *(const vf4*)&Cf[row * LDCf + c4];
            __builtin_nontemporal_store(v,
                (vf4*)(out + (size_t)(m0 + half * 64 + row) * EMB + n0 + c4));
        }
    }
}

// ---------------- attention: double-buffered phases ------------------------
// Phase 1: K staged via LDS in 128-row chunks, DOUBLE-BUFFERED (one barrier
// per chunk); register prefetch. Phase 3: V frags direct from VF into regs
// (prefetched one chunk ahead), PT double-buffered (one barrier per chunk).
// setprio(1) around MFMA clusters.
__global__ __launch_bounds__(512, 4) void attn_kernel(
    const f16* __restrict__ qh, const f16* __restrict__ kh,
    const f16* __restrict__ vf,
    float* __restrict__ attn, f16* __restrict__ ch)
{
    __shared__ f16 SM[16384];    // 32 KB: ph1 K dbuf 2x8192; ph3 PT dbuf 2x4096
    __shared__ float RMAX[8][16];
    __shared__ float RSUM[8][16];

    const int lid = blockIdx.y * gridDim.x + blockIdx.x;  // 0..2047
    const int xs  = lid & 7;
    const int jj  = lid >> 3;
    const int bh  = xs * 8 + (jj >> 5);
    const int qt  = jj & 31;

    const int tid  = threadIdx.x;
    const int w    = tid >> 6;
    const int grp  = w >> 2;
    const int wg   = w & 3;
    const int lane = tid & 63;
    const int c    = lane & 15;
    const int g    = lane >> 4;

    const size_t bhS = (size_t)bh * SEQ;
    const f16* VFb = vf + ((size_t)bh << 16);

    // Q A-frags, pre-scaled by 0.125 (exact)
    f16x8 Q0, Q1;
    {
        size_t qb = (bhS + qt * 32 + grp * 16 + c) * HD + g * 8;
        Q0 = *(const f16x8*)(qh + qb);
        Q1 = *(const f16x8*)(qh + qb + 32);
        Q0 *= (f16)0.125f;
        Q1 *= (f16)0.125f;
    }

    f32x4 s4[16];
#pragma unroll
    for (int kt = 0; kt < 16; ++kt) s4[kt] = (f32x4){0.f, 0.f, 0.f, 0.f};

    // ---- phase 1: QK^T, K 128-row chunks, LDS double-buffer ----
    const int srow = tid >> 3;           // 0..63
    const int sch  = tid & 7;
    f16x8 kb0, kb1;
    {   // chunk 0 -> buf0
        size_t ga = (bhS + srow) * HD + sch * 8;
        f16x8 a0 = *(const f16x8*)(kh + ga);
        f16x8 a1 = *(const f16x8*)(kh + ga + (size_t)64 * HD);
        int r1 = srow + 64;
        *(f16x8*)&SM[srow * 64 + (sch ^ (srow & 7)) * 8] = a0;
        *(f16x8*)&SM[r1 * 64 + (sch ^ (r1 & 7)) * 8]     = a1;
    }
    {   // chunk 1 in flight
        size_t ga = (bhS + 128 + srow) * HD + sch * 8;
        kb0 = *(const f16x8*)(kh + ga);
        kb1 = *(const f16x8*)(kh + ga + (size_t)64 * HD);
    }
    __syncthreads();
#pragma unroll
    for (int kt2 = 0; kt2 < 8; ++kt2) {
        const int base = (kt2 & 1) * 8192;
        __builtin_amdgcn_s_setprio(1);
#pragma unroll
        for (int half = 0; half < 2; ++half) {
            const int krow = half * 64 + wg * 16 + c;
            const int ks7  = krow & 7;
            f16x8 B0 = *(const f16x8*)&SM[base + krow * 64 + ((0 + g) ^ ks7) * 8];
            f16x8 B1 = *(const f16x8*)&SM[base + krow * 64 + ((4 + g) ^ ks7) * 8];
            s4[kt2 * 2 + half] = __builtin_amdgcn_mfma_f32_16x16x32_f16(
                Q0, B0, s4[kt2 * 2 + half], 0, 0, 0);
            s4[kt2 * 2 + half] = __builtin_amdgcn_mfma_f32_16x16x32_f16(
                Q1, B1, s4[kt2 * 2 + half], 0, 0, 0);
        }
        __builtin_amdgcn_s_setprio(0);
        if (kt2 < 7) {
            const int nb = 8192 - base;
            int r1 = srow + 64;
            *(f16x8*)&SM[nb + srow * 64 + (sch ^ (srow & 7)) * 8] = kb0;
            *(f16x8*)&SM[nb + r1 * 64 + (sch ^ (r1 & 7)) * 8]     = kb1;
            if (kt2 < 6) {
                size_t ga = (bhS + (kt2 + 2) * 128 + srow) * HD + sch * 8;
                kb0 = *(const f16x8*)(kh + ga);
                kb1 = *(const f16x8*)(kh + ga + (size_t)64 * HD);
            }
            __syncthreads();
        }
    }

    // ---- softmax (per 4-wave group; scale folded into Q) ----
    float m_[4], l_[4];
#pragma unroll
    for (int r = 0; r < 4; ++r) {
        float mm = -1e30f;
#pragma unroll
        for (int kt = 0; kt < 16; ++kt) mm = fmaxf(mm, s4[kt][r]);
        m_[r] = mm;
    }
#pragma unroll
    for (int off = 1; off < 16; off <<= 1)
#pragma unroll
        for (int r = 0; r < 4; ++r) m_[r] = fmaxf(m_[r], __shfl_xor(m_[r], off));
    if (c == 0) {
#pragma unroll
        for (int r = 0; r < 4; ++r) RMAX[w][g * 4 + r] = m_[r];
    }
    __syncthreads();
#pragma unroll
    for (int r = 0; r < 4; ++r)
        m_[r] = fmaxf(fmaxf(RMAX[grp * 4 + 0][g * 4 + r], RMAX[grp * 4 + 1][g * 4 + r]),
                      fmaxf(RMAX[grp * 4 + 2][g * 4 + r], RMAX[grp * 4 + 3][g * 4 + r]));
#pragma unroll
    for (int r = 0; r < 4; ++r) {
        float ss = 0.f;
#pragma unroll
        for (int kt = 0; kt < 16; ++kt) {
            float p = __expf(s4[kt][r] - m_[r]);
            s4[kt][r] = p;
            ss += p;
        }
        l_[r] = ss;
    }
#pragma unroll
    for (int off = 1; off < 16; off <<= 1)
#pragma unroll
        for (int r = 0; r < 4; ++r) l_[r] += __shfl_xor(l_[r], off);
    if (c == 0) {
#pragma unroll
        for (int r = 0; r < 4; ++r) RSUM[w][g * 4 + r] = l_[r];
    }
    __syncthreads();
#pragma unroll
    for (int r = 0; r < 4; ++r)
        l_[r] = 1.f / (RSUM[grp * 4 + 0][g * 4 + r] + RSUM[grp * 4 + 1][g * 4 + r] +
                       RSUM[grp * 4 + 2][g * 4 + r] + RSUM[grp * 4 + 3][g * 4 + r]);

    // ---- phase 3: PV (register V frags, prefetched) + PT dbuf ----
    f32x4 ctx = (f32x4){0.f, 0.f, 0.f, 0.f};
    float* ap = attn + (bhS + qt * 32) * SEQ;
    const int dmy = wg * 16 + c;

#define WRITE_PT(CTG, BASE)                                                    \
    {                                                                          \
        _Pragma("unroll")                                                      \
        for (int kt2 = 0; kt2 < 2; ++kt2) {                                    \
            const int ktg = (CTG) * 2 + kt2;                                   \
            const int chh = (kt2 * 64 + wg * 16 + c) >> 3;                     \
            _Pragma("unroll")                                                  \
            for (int r = 0; r < 4; ++r) {                                      \
                const int q = g * 4 + r;                                       \
                float val = s4[ktg][r] * l_[r];                                \
                int schP = chh ^ q;                                            \
                SM[(BASE) + (grp * 16 + q) * 128 + schP * 8 + (c & 7)] =       \
                    (f16)val;                                                  \
            }                                                                  \
        }                                                                      \
    }

    f16x8 Va[4], Vb[4];
#pragma unroll
    for (int ks = 0; ks < 4; ++ks)
        Va[ks] = *(const f16x8*)(VFb + ks * 2048 + dmy * 32 + g * 8);
    WRITE_PT(0, 0);
    __syncthreads();

#pragma unroll
    for (int ct = 0; ct < 8; ++ct) {
        const int pb = (ct & 1) * 4096;
        if (ct < 7) {
#pragma unroll
            for (int ks = 0; ks < 4; ++ks)
                Vb[ks] = *(const f16x8*)(VFb + ((ct + 1) * 4 + ks) * 2048 +
                                         dmy * 32 + g * 8);
        }
        __builtin_amdgcn_s_setprio(1);
#pragma unroll
        for (int ks = 0; ks < 4; ++ks) {
            f16x8 Pa = *(const f16x8*)&SM[pb + (grp * 16 + c) * 128 +
                                          (((ks * 4 + g) ^ c) & 15) * 8];
            ctx = __builtin_amdgcn_mfma_f32_16x16x32_f16(Pa, Va[ks], ctx, 0, 0, 0);
        }
        __builtin_amdgcn_s_setprio(0);
        // coalesced attn write from PT[pb]
#pragma unroll
        for (int t = 0; t < 2; ++t) {
            int idx = tid + (t << 9);        // 0..1023
            int row = idx >> 5;              // 0..31
            int col = (idx & 31) << 2;
            int swz = (col >> 3) ^ (row & 15);
            f16x4 pv = *(const f16x4*)&SM[pb + row * 128 + swz * 8 + (col & 7)];
            vf4 o = __builtin_convertvector(pv, vf4);
            __builtin_nontemporal_store(o,
                (vf4*)(ap + (size_t)row * SEQ + ct * 128 + col));
        }
        if (ct < 7) {
            WRITE_PT(ct + 1, 4096 - pb);
            __syncthreads();
        }
#pragma unroll
        for (int ks = 0; ks < 4; ++ks) Va[ks] = Vb[ks];
    }
#undef WRITE_PT

    // ---- epilogue: ctx -> ch (merged (b,s,h*d), fp16) ----
    {
        int b = bh >> 4, h = bh & 15;
#pragma unroll
        for (int r = 0; r < 4; ++r) {
            int qrow = qt * 32 + grp * 16 + g * 4 + r;
            size_t a = (((size_t)(b * SEQ + qrow)) << 10) + h * HD + wg * 16 + c;
            ch[a] = (f16)ctx[r];
        }
    }
}

extern "C" void kernel_launch(void* const* d_in, const int* in_sizes, int n_in,
                              void* d_out, int out_size, void* d_ws, size_t ws_size,
                              hipStream_t stream) {
    const float* x  = (const float*)d_in[0];
    const float* wq = (const float*)d_in[1];
    const float* bq = (const float*)d_in[2];
    const float* wk = (const float*)d_in[3];
    const float* bk = (const float*)d_in[4];
    const float* wv = (const float*)d_in[5];
    const float* bv = (const float*)d_in[6];
    const float* wo = (const float*)d_in[7];
    const float* bo = (const float*)d_in[8];

    float* out      = (float*)d_out;
    float* attn_out = out + (size_t)BATCH * SEQ * EMB;

    const size_t MK = (size_t)MTOT * 1024;
    f16* ws16 = (f16*)d_ws;
    f16* xh = ws16;                      // reused as ch after qkv
    f16* wh = xh + MK;                   // 4 planes of 1024x1024
    f16* qh = wh + ((size_t)4 << 20);
    f16* kh = qh + MK;
    f16* vf = kh + MK;
    f16* ch = xh;

    convert_all<<<8192, 256, 0, stream>>>(x, wq, wk, wv, wo, xh, wh);

    qkv_mfma<<<dim3(EMB / BN, MTOT / BM, 3), 256, 0, stream>>>(
        xh, wh, bq, bk, bv, qh, kh, vf);

    attn_kernel<<<dim3(SEQ / 32, BATCH * HEADS), 512, 0, stream>>>(
        qh, kh, vf, attn_out, ch);

    oproj_mfma<<<dim3(EMB / BN, MTOT / BM), 256, 0, stream>>>(
        ch, wh, bo, out);
}

// Round 16
// 137.561 us; speedup vs baseline: 1.0674x; 1.0674x over previous
//
#include <hip/hip_runtime.h>
#include <math.h>

#define BATCH 4
#define SEQ   1024
#define EMB   1024
#define HEADS 16
#define HD    64
#define MTOT  (BATCH*SEQ)   // 4096

typedef float    f32x4 __attribute__((ext_vector_type(4)));
typedef float    vf4   __attribute__((ext_vector_type(4)));
typedef _Float16 f16;
typedef _Float16 f16x4 __attribute__((ext_vector_type(4)));
typedef _Float16 f16x8 __attribute__((ext_vector_type(8)));

// T4 barrier: drain LDS queue (lgkmcnt) before rendezvous — required for
// cross-wave LDS hand-off (r15 raced without it) — but do NOT drain vmcnt,
// so global register-prefetches stay in flight across the barrier.
// (__syncthreads would emit s_waitcnt vmcnt(0) lgkmcnt(0).)
#define BAR_LDS() do { asm volatile("s_waitcnt lgkmcnt(0)" ::: "memory"); \
                       __builtin_amdgcn_s_barrier(); \
                       asm volatile("" ::: "memory"); } while (0)

// ---- conversion: x (4096 rows) + 4 weights (4096 rows) -> fp16 ------------
__global__ __launch_bounds__(256) void convert_all(
    const float* __restrict__ x,
    const float* __restrict__ wq, const float* __restrict__ wk,
    const float* __restrict__ wv, const float* __restrict__ wo,
    f16* __restrict__ xh, f16* __restrict__ wh)
{
    const int bid = blockIdx.x;          // 0..8191
    const float* src;
    f16* dst;
    if (bid < 4096) {
        src = x + ((size_t)bid << 10);
        dst = xh + ((size_t)bid << 10);
    } else {
        int t  = bid - 4096;
        int mi = t >> 10, r = t & 1023;
        const float* in = (mi == 0) ? wq : (mi == 1) ? wk : (mi == 2) ? wv : wo;
        src = in + ((size_t)r << 10);
        dst = wh + ((size_t)mi << 20) + ((size_t)r << 10);
    }
    int o = threadIdx.x << 2;
    float4 v = *(const float4*)(src + o);
    f16x4 h;
    h.x = (f16)v.x; h.y = (f16)v.y; h.z = (f16)v.z; h.w = (f16)v.w;
    *(f16x4*)(dst + o) = h;
}

// ---- fp16 single-pass MFMA GEMM tile: C = A @ W^T -------------------------
#define BM  128
#define BN  128
#define LDT 72   // f16 elems per padded LDS row

__device__ __forceinline__ void mfma_gemm_tile(
    const f16* __restrict__ A, const f16* __restrict__ B,
    int m0, int n0, f32x4 acc[4][4], f16* SMEM)
{
    f16* As = SMEM;
    f16* Bs = SMEM + BM * LDT;
    const int tid  = threadIdx.x;
    const int lane = tid & 63;
    const int w    = tid >> 6;
    const int wr   = w >> 1, wc = w & 1;
    const int fr   = lane & 15;
    const int kb   = lane >> 4;

#pragma unroll
    for (int i = 0; i < 4; ++i)
#pragma unroll
        for (int j = 0; j < 4; ++j) acc[i][j] = (f32x4){0.f, 0.f, 0.f, 0.f};

    f16x8 ra[4], rb[4];
#define LOAD_STEP(KT)                                                          \
    {                                                                          \
        int k0 = (KT) * 64;                                                    \
        _Pragma("unroll")                                                      \
        for (int i = 0; i < 4; ++i) {                                          \
            int c = tid + (i << 8);                                            \
            int row = c >> 3, cc = (c & 7) << 3;                               \
            ra[i] = *(const f16x8*)(A + ((size_t)(m0 + row) << 10) + k0 + cc); \
            rb[i] = *(const f16x8*)(B + ((size_t)(n0 + row) << 10) + k0 + cc); \
        }                                                                      \
    }

    LOAD_STEP(0);
    for (int kt = 0; kt < 16; ++kt) {
        __syncthreads();
#pragma unroll
        for (int i = 0; i < 4; ++i) {
            int c = tid + (i << 8);
            int row = c >> 3, cc = (c & 7) << 3;
            *(f16x8*)&As[row * LDT + cc] = ra[i];
            *(f16x8*)&Bs[row * LDT + cc] = rb[i];
        }
        if (kt + 1 < 16) LOAD_STEP(kt + 1);
        __syncthreads();
#pragma unroll
        for (int kc = 0; kc < 2; ++kc) {
            f16x8 aF[4], bF[4];
#pragma unroll
            for (int i = 0; i < 4; ++i)
                aF[i] = *(const f16x8*)&As[(wr * 64 + i * 16 + fr) * LDT + kc * 32 + kb * 8];
#pragma unroll
            for (int j = 0; j < 4; ++j)
                bF[j] = *(const f16x8*)&Bs[(wc * 64 + j * 16 + fr) * LDT + kc * 32 + kb * 8];
#pragma unroll
            for (int i = 0; i < 4; ++i)
#pragma unroll
                for (int j = 0; j < 4; ++j)
                    acc[i][j] = __builtin_amdgcn_mfma_f32_16x16x32_f16(
                        aF[i], bF[j], acc[i][j], 0, 0, 0);
        }
    }
#undef LOAD_STEP
}

// QKV: writes Q,K fp16 (b,h,s,d); V transposed fp16 (b,h,d,s).
__global__ __launch_bounds__(256, 2) void qkv_mfma(
    const f16* __restrict__ xh, const f16* __restrict__ wh,
    const float* __restrict__ bq, const float* __restrict__ bk,
    const float* __restrict__ bv,
    f16* __restrict__ qh, f16* __restrict__ kh, f16* __restrict__ vth)
{
    __shared__ __align__(16) f16 SMEM[2 * BM * LDT];   // 36 KB
    const int z = blockIdx.z;
    const f16* Bm = wh + ((size_t)z << 20);
    const float* bias = (z == 0) ? bq : (z == 1) ? bk : bv;
    const int m0 = blockIdx.y * BM, n0 = blockIdx.x * BN;
    f32x4 acc[4][4];
    mfma_gemm_tile(xh, Bm, m0, n0, acc, SMEM);

    const int tid  = threadIdx.x;
    const int lane = tid & 63;
    const int w    = tid >> 6;
    const int wr   = w >> 1, wc = w & 1;
    const int fr   = lane & 15;
    const int rg   = lane >> 4;
    const int LDC  = 136;
    const int b = m0 >> 10, sbase = m0 & 1023;

    __syncthreads();   // gemm LDS reads done
    if (z < 2) {
        f16* p = (z == 0) ? qh : kh;
#pragma unroll
        for (int i = 0; i < 4; ++i)
#pragma unroll
            for (int j = 0; j < 4; ++j) {
                int nn = wc * 64 + j * 16 + fr;
                float bv_ = bias[n0 + nn];
#pragma unroll
                for (int r = 0; r < 4; ++r) {
                    int mm = wr * 64 + i * 16 + rg * 4 + r;
                    SMEM[mm * LDC + nn] = (f16)(acc[i][j][r] + bv_);
                }
            }
        __syncthreads();
#pragma unroll
        for (int t = 0; t < 8; ++t) {
            int idx = tid + (t << 8);
            int row = idx >> 4, ch = idx & 15;
            int n8 = n0 + ch * 8;
            int h = n8 >> 6, d = n8 & 63;
            f16x8 v = *(const f16x8*)&SMEM[row * LDC + ch * 8];
            *(f16x8*)(p + ((size_t)((b * HEADS + h) * SEQ + sbase + row)) * HD + d) = v;
        }
    } else {
        // transposed bounce: SMEM[n][m] so V stores are s-contiguous
#pragma unroll
        for (int i = 0; i < 4; ++i)
#pragma unroll
            for (int j = 0; j < 4; ++j) {
                int nn = wc * 64 + j * 16 + fr;
                float bv_ = bias[n0 + nn];
#pragma unroll
                for (int r = 0; r < 4; ++r) {
                    int mm = wr * 64 + i * 16 + rg * 4 + r;
                    SMEM[nn * LDC + mm] = (f16)(acc[i][j][r] + bv_);
                }
            }
        __syncthreads();
#pragma unroll
        for (int t = 0; t < 8; ++t) {
            int idx = tid + (t << 8);
            int col = idx >> 4, mch = idx & 15;
            int n8 = n0 + col;
            int h = n8 >> 6, d = n8 & 63;
            f16x8 v = *(const f16x8*)&SMEM[col * LDC + mch * 8];
            *(f16x8*)(vth + ((size_t)((b * HEADS + h) * HD + d)) * SEQ + sbase + mch * 8) = v;
        }
    }
}

// OPROJ: ctx fp16 @ wo^T + bo -> out fp32, LDS-bounced float4 stores.
__global__ __launch_bounds__(256, 2) void oproj_mfma(
    const f16* __restrict__ ch, const f16* __restrict__ wh,
    const float* __restrict__ bo, float* __restrict__ out)
{
    __shared__ __align__(16) f16 SMEM[2 * BM * LDT];
    const f16* Bm = wh + ((size_t)3 << 20);
    const int m0 = blockIdx.y * BM, n0 = blockIdx.x * BN;
    f32x4 acc[4][4];
    mfma_gemm_tile(ch, Bm, m0, n0, acc, SMEM);

    const int tid  = threadIdx.x;
    const int lane = tid & 63;
    const int w    = tid >> 6;
    const int wr   = w >> 1, wc = w & 1;
    const int fr   = lane & 15;
    const int rg   = lane >> 4;
    float* Cf = (float*)SMEM;            // 64 x 132 fp32 half-tile
    const int LDCf = 132;

#pragma unroll
    for (int half = 0; half < 2; ++half) {
        __syncthreads();
        if (wr == half) {
#pragma unroll
            for (int i = 0; i < 4; ++i)
#pragma unroll
                for (int j = 0; j < 4; ++j) {
                    int nn = wc * 64 + j * 16 + fr;
                    float bv_ = bo[n0 + nn];
#pragma unroll
                    for (int r = 0; r < 4; ++r)
                        Cf[(i * 16 + rg * 4 + r) * LDCf + nn] = acc[i][j][r] + bv_;
                }
        }
        __syncthreads();
#pragma unroll
        for (int t = 0; t < 8; ++t) {
            int idx = tid + (t << 8);
            int row = idx >> 5, c4 = (idx & 31) << 2;
            vf4 v = *(const vf4*)&Cf[row * LDCf + c4];
            __builtin_nontemporal_store(v,
                (vf4*)(out + (size_t)(m0 + half * 64 + row) * EMB + n0 + c4));
        }
    }
}

// ---------------- attention: K11 structure + lgkm-only barriers ------------
// Identical to the 138-us kernel except the four barrier sites use
// s_waitcnt lgkmcnt(0) + raw s_barrier (LDS drained -> no r15 race; vmcnt
// NOT drained -> kn/vn register prefetches survive the barrier).
__global__ __launch_bounds__(512, 4) void attn_kernel(
    const f16* __restrict__ qh, const f16* __restrict__ kh,
    const f16* __restrict__ vth,
    float* __restrict__ attn, f16* __restrict__ ch)
{
    __shared__ f16 SM[12288];   // 24 KB: ph1 K [0,4096); ph3 VT [0,8192), PT [8192,12288)
    __shared__ float RMAX[8][16];
    __shared__ float RSUM[8][16];

    const int lid = blockIdx.y * gridDim.x + blockIdx.x;  // 0..2047
    const int xs  = lid & 7;
    const int jj  = lid >> 3;
    const int bh  = xs * 8 + (jj >> 5);
    const int qt  = jj & 31;

    const int tid  = threadIdx.x;
    const int w    = tid >> 6;
    const int grp  = w >> 2;
    const int wg   = w & 3;
    const int lane = tid & 63;
    const int c    = lane & 15;
    const int g    = lane >> 4;

    const size_t bhS = (size_t)bh * SEQ;

    // Q A-frags: lane holds q-row = qt*32 + grp*16 + c
    f16x8 Q0, Q1;
    {
        size_t qb = (bhS + qt * 32 + grp * 16 + c) * HD + g * 8;
        Q0 = *(const f16x8*)(qh + qb);
        Q1 = *(const f16x8*)(qh + qb + 32);
    }

    f32x4 s4[16];
#pragma unroll
    for (int kt = 0; kt < 16; ++kt) s4[kt] = (f32x4){0.f, 0.f, 0.f, 0.f};

    // ---- phase 1: QK^T, K in 128-row LDS chunks, register prefetch ----
    const int srow = tid >> 3;           // 0..63
    const int sch  = tid & 7;
    f16x8 kc0, kc1, kn0, kn1;
    {
        size_t ga = (bhS + srow) * HD + sch * 8;
        kc0 = *(const f16x8*)(kh + ga);
        kc1 = *(const f16x8*)(kh + ga + (size_t)64 * HD);
    }
#pragma unroll
    for (int kt2 = 0; kt2 < 8; ++kt2) {
        BAR_LDS();      // prev chunk LDS reads drained; vmcnt stays in flight
        {
            int r1 = srow + 64;
            *(f16x8*)&SM[srow * 64 + (sch ^ (srow & 7)) * 8] = kc0;
            *(f16x8*)&SM[r1 * 64 + (sch ^ (r1 & 7)) * 8]     = kc1;
        }
        if (kt2 < 7) {
            size_t ga = (bhS + (kt2 + 1) * 128 + srow) * HD + sch * 8;
            kn0 = *(const f16x8*)(kh + ga);
            kn1 = *(const f16x8*)(kh + ga + (size_t)64 * HD);
        }
        BAR_LDS();      // my LDS writes complete & visible; kn loads in flight
#pragma unroll
        for (int half = 0; half < 2; ++half) {
            const int krow = half * 64 + wg * 16 + c;
            const int ks7  = krow & 7;
            f16x8 B0 = *(const f16x8*)&SM[krow * 64 + ((0 + g) ^ ks7) * 8];
            f16x8 B1 = *(const f16x8*)&SM[krow * 64 + ((4 + g) ^ ks7) * 8];
            s4[kt2 * 2 + half] = __builtin_amdgcn_mfma_f32_16x16x32_f16(
                Q0, B0, s4[kt2 * 2 + half], 0, 0, 0);
            s4[kt2 * 2 + half] = __builtin_amdgcn_mfma_f32_16x16x32_f16(
                Q1, B1, s4[kt2 * 2 + half], 0, 0, 0);
        }
        kc0 = kn0; kc1 = kn1;
    }

    // ---- softmax (per 4-wave group) ----
    float m_[4], l_[4];
#pragma unroll
    for (int r = 0; r < 4; ++r) {
        float mm = -1e30f;
#pragma unroll
        for (int kt = 0; kt < 16; ++kt) {
            s4[kt][r] *= 0.125f;
            mm = fmaxf(mm, s4[kt][r]);
        }
        m_[r] = mm;
    }
#pragma unroll
    for (int off = 1; off < 16; off <<= 1)
#pragma unroll
        for (int r = 0; r < 4; ++r) m_[r] = fmaxf(m_[r], __shfl_xor(m_[r], off));
    if (c == 0) {
#pragma unroll
        for (int r = 0; r < 4; ++r) RMAX[w][g * 4 + r] = m_[r];
    }
    __syncthreads();
#pragma unroll
    for (int r = 0; r < 4; ++r)
        m_[r] = fmaxf(fmaxf(RMAX[grp * 4 + 0][g * 4 + r], RMAX[grp * 4 + 1][g * 4 + r]),
                      fmaxf(RMAX[grp * 4 + 2][g * 4 + r], RMAX[grp * 4 + 3][g * 4 + r]));
#pragma unroll
    for (int r = 0; r < 4; ++r) {
        float ss = 0.f;
#pragma unroll
        for (int kt = 0; kt < 16; ++kt) {
            float p = __expf(s4[kt][r] - m_[r]);
            s4[kt][r] = p;
            ss += p;
        }
        l_[r] = ss;
    }
#pragma unroll
    for (int off = 1; off < 16; off <<= 1)
#pragma unroll
        for (int r = 0; r < 4; ++r) l_[r] += __shfl_xor(l_[r], off);
    if (c == 0) {
#pragma unroll
        for (int r = 0; r < 4; ++r) RSUM[w][g * 4 + r] = l_[r];
    }
    __syncthreads();
#pragma unroll
    for (int r = 0; r < 4; ++r)
        l_[r] = 1.f / (RSUM[grp * 4 + 0][g * 4 + r] + RSUM[grp * 4 + 1][g * 4 + r] +
                       RSUM[grp * 4 + 2][g * 4 + r] + RSUM[grp * 4 + 3][g * 4 + r]);

    // ---- phase 3: PV + coalesced attn write (8 chunks of 128 k), V prefetch
    f32x4 ctx = (f32x4){0.f, 0.f, 0.f, 0.f};
    float* ap = attn + (bhS + qt * 32) * SEQ;
    const int vrow0 = tid >> 4;          // 0..31 (t adds 32)
    const int vch   = tid & 15;

    f16x8 vc[2], vn[2];
#pragma unroll
    for (int t = 0; t < 2; ++t) {
        int drow = vrow0 + t * 32;
        vc[t] = *(const f16x8*)(vth + ((size_t)bh * HD + drow) * SEQ + vch * 8);
    }
#pragma unroll
    for (int ct = 0; ct < 8; ++ct) {
        BAR_LDS();      // prev chunk LDS reads drained; vmcnt stays in flight
#pragma unroll
        for (int t = 0; t < 2; ++t) {
            int drow = vrow0 + t * 32;
            int swz = vch ^ (drow & 7);
            *(f16x8*)&SM[drow * 128 + swz * 8] = vc[t];
        }
        if (ct < 7) {
#pragma unroll
            for (int t = 0; t < 2; ++t) {
                int drow = vrow0 + t * 32;
                vn[t] = *(const f16x8*)(vth + ((size_t)bh * HD + drow) * SEQ +
                                        (ct + 1) * 128 + vch * 8);
            }
        }
        // normalized P -> PT fp16 (swizzled A-frag layout)
#pragma unroll
        for (int kt2 = 0; kt2 < 2; ++kt2) {
            const int ktg = ct * 2 + kt2;
            const int chh = (kt2 * 64 + wg * 16 + c) >> 3;
#pragma unroll
            for (int r = 0; r < 4; ++r) {
                const int q = g * 4 + r;
                float val = s4[ktg][r] * l_[r];
                int schP = chh ^ q;
                SM[8192 + (grp * 16 + q) * 128 + schP * 8 + (c & 7)] = (f16)val;
            }
        }
        BAR_LDS();      // LDS writes visible; vn loads stay in flight
        // PV: A = P frags (own group), B = V^T frags (shared)
        const int drow = wg * 16 + c;
        const int ds7  = drow & 7;
#pragma unroll
        for (int ks = 0; ks < 4; ++ks) {
            f16x8 Vh = *(const f16x8*)&SM[drow * 128 + ((ks * 4 + g) ^ ds7) * 8];
            f16x8 Pa = *(const f16x8*)&SM[8192 + (grp * 16 + c) * 128 + (((ks * 4 + g) ^ c) & 15) * 8];
            ctx = __builtin_amdgcn_mfma_f32_16x16x32_f16(Pa, Vh, ctx, 0, 0, 0);
        }
        // coalesced attn write: PT readback, convert, float4 nontemporal
#pragma unroll
        for (int t = 0; t < 2; ++t) {
            int idx = tid + (t << 9);        // 0..1023
            int row = idx >> 5;              // 0..31
            int c4  = idx & 31;
            int col = c4 << 2;
            int swz = (col >> 3) ^ (row & 15);
            f16x4 pv = *(const f16x4*)&SM[8192 + row * 128 + swz * 8 + (col & 7)];
            vf4 o = __builtin_convertvector(pv, vf4);
            __builtin_nontemporal_store(o,
                (vf4*)(ap + (size_t)row * SEQ + ct * 128 + col));
        }
        vc[0] = vn[0]; vc[1] = vn[1];
    }

    // ---- epilogue: ctx -> ch (merged (b,s,h*d), fp16) ----
    {
        int b = bh >> 4, h = bh & 15;
#pragma unroll
        for (int r = 0; r < 4; ++r) {
            int qrow = qt * 32 + grp * 16 + g * 4 + r;
            size_t a = (((size_t)(b * SEQ + qrow)) << 10) + h * HD + wg * 16 + c;
            ch[a] = (f16)ctx[r];
        }
    }
}

extern "C" void kernel_launch(void* const* d_in, const int* in_sizes, int n_in,
                              void* d_out, int out_size, void* d_ws, size_t ws_size,
                              hipStream_t stream) {
    const float* x  = (const float*)d_in[0];
    const float* wq = (const float*)d_in[1];
    const float* bq = (const float*)d_in[2];
    const float* wk = (const float*)d_in[3];
    const float* bk = (const float*)d_in[4];
    const float* wv = (const float*)d_in[5];
    const float* bv = (const float*)d_in[6];
    const float* wo = (const float*)d_in[7];
    const float* bo = (const float*)d_in[8];

    float* out      = (float*)d_out;
    float* attn_out = out + (size_t)BATCH * SEQ * EMB;

    const size_t MK = (size_t)MTOT * 1024;
    f16* ws16 = (f16*)d_ws;
    f16* xh  = ws16;                     // reused as ch after qkv
    f16* wh  = xh + MK;                  // 4 planes of 1024x1024
    f16* qh  = wh + ((size_t)4 << 20);
    f16* kh  = qh + MK;
    f16* vth = kh + MK;
    f16* ch  = xh;

    convert_all<<<8192, 256, 0, stream>>>(x, wq, wk, wv, wo, xh, wh);

    qkv_mfma<<<dim3(EMB / BN, MTOT / BM, 3), 256, 0, stream>>>(
        xh, wh, bq, bk, bv, qh, kh, vth);

    attn_kernel<<<dim3(SEQ / 32, BATCH * HEADS), 512, 0, stream>>>(
        qh, kh, vth, attn_out, ch);

    oproj_mfma<<<dim3(EMB / BN, MTOT / BM), 256, 0, stream>>>(
        ch, wh, bo, out);
}